// Round 1
// baseline (400.007 us; speedup 1.0000x reference)
//
#include <hip/hip_runtime.h>
#include <hip/hip_bf16.h>
#include <stdint.h>

// Problem constants (match reference)
#define OUT_DIM 4096
#define IN_DIM  4096
#define GROUPSZ 128
#define NGROUPS 32
#define M_TOTAL 8192   // 4 * 2048
#define EPS_Q   1e-12f

// GEMM tiling
#define BM 128
#define BN 128
#define BK 32

typedef float f32x4  __attribute__((ext_vector_type(4)));
typedef float float4v __attribute__((ext_vector_type(4)));
typedef short bf16x8 __attribute__((ext_vector_type(8)));   // 8 bf16 in 4 VGPRs (guide §3)

// Manual RNE float->bf16 (matches numpy/jax astype for finite values)
static __device__ __forceinline__ short f2bf(float f) {
    union { float f; unsigned u; } v; v.f = f;
    unsigned r = v.u + 0x7fffu + ((v.u >> 16) & 1u);
    return (short)(r >> 16);
}

// async global->LDS, 16B per lane, linear LDS dest (wave-uniform base + lane*16)
#define GLOAD16(gp, lp) __builtin_amdgcn_global_load_lds( \
    (const __attribute__((address_space(1))) void*)(gp),  \
    (__attribute__((address_space(3))) void*)(lp), 16, 0, 0)

// ---------------------------------------------------------------------------
// Kernel 1: dequantize W = norms_p * unit(q_p) + norms_r * unit(q_r), bf16 out
// one wave per (out_row, group); 2 elements per lane
// ---------------------------------------------------------------------------
__global__ __launch_bounds__(256) void dequant_kernel(
    const float* __restrict__ norms_p, const float* __restrict__ norms_r,
    const int* __restrict__ idx_p, const int* __restrict__ idx_r,
    short* __restrict__ W)
{
    const int gid  = (int)((blockIdx.x * 256u + threadIdx.x) >> 6); // group id
    const int lane = threadIdx.x & 63;
    const size_t base = (size_t)gid * GROUPSZ;

    const int ip0 = idx_p[base + lane];
    const int ip1 = idx_p[base + lane + 64];
    const int ir0 = idx_r[base + lane];
    const int ir1 = idx_r[base + lane + 64];

    // levels: linspace(-1,1,16) and linspace(-1,1,4)
    const float qp0 = -1.f + (2.f / 15.f) * (float)ip0;
    const float qp1 = -1.f + (2.f / 15.f) * (float)ip1;
    const float qr0 = -1.f + (2.f / 3.f)  * (float)ir0;
    const float qr1 = -1.f + (2.f / 3.f)  * (float)ir1;

    float ssp = qp0 * qp0 + qp1 * qp1;
    float ssr = qr0 * qr0 + qr1 * qr1;
    #pragma unroll
    for (int m = 32; m >= 1; m >>= 1) {
        ssp += __shfl_xor(ssp, m);
        ssr += __shfl_xor(ssr, m);
    }
    const float sp = norms_p[gid] / sqrtf(ssp + EPS_Q);
    const float sr = norms_r[gid] / sqrtf(ssr + EPS_Q);

    W[base + lane]      = f2bf(qp0 * sp + qr0 * sr);
    W[base + lane + 64] = f2bf(qp1 * sp + qr1 * sr);
}

// ---------------------------------------------------------------------------
// Kernel 2: cast x (fp32) -> bf16, 8 elems / thread
// ---------------------------------------------------------------------------
__global__ __launch_bounds__(256) void cast_kernel(
    const float* __restrict__ x, short* __restrict__ xb)
{
    const size_t i = ((size_t)blockIdx.x * 256u + threadIdx.x) * 8u;
    float4v a = *(const float4v*)(x + i);
    float4v b = *(const float4v*)(x + i + 4);
    bf16x8 o;
    o[0] = f2bf(a[0]); o[1] = f2bf(a[1]); o[2] = f2bf(a[2]); o[3] = f2bf(a[3]);
    o[4] = f2bf(b[0]); o[5] = f2bf(b[1]); o[6] = f2bf(b[2]); o[7] = f2bf(b[3]);
    *(bf16x8*)(xb + i) = o;
}

// ---------------------------------------------------------------------------
// Kernel 3: C[M][N] = A[M][K] @ B[N][K]^T + bias, bf16 in / fp32 out
// 128x128 tile, BK=32, 4 waves, each wave = 64x64 (4x4 frags of 16x16x32)
// global_load_lds staging with pre-swizzled global source (chunk ^= (row>>1)&3)
// ---------------------------------------------------------------------------
__global__ __launch_bounds__(256) void gemm_kernel(
    const short* __restrict__ A,   // [M][K] bf16
    const short* __restrict__ B,   // [N][K] bf16
    const float* __restrict__ bias,
    float* __restrict__ C)
{
    __shared__ short lsA[BM * BK];   // 8 KB, swizzled chunk layout
    __shared__ short lsB[BN * BK];   // 8 KB

    const int tid  = threadIdx.x;
    const int lane = tid & 63;
    const int wid  = tid >> 6;       // 0..3
    const int wr   = wid >> 1;       // wave row (0..1)
    const int wc   = wid & 1;        // wave col (0..1)

    const int nt = blockIdx.x & 31;          // N / BN = 32
    const int mt = blockIdx.x >> 5;          // M / BM = 64
    const size_t brow = (size_t)mt * BM;
    const size_t bcol = (size_t)nt * BN;

    // staging: slot s in [0,512): row r = s>>2, chunk c = s&3 (16B chunks of a 64B row)
    // LDS linear; global source pre-swizzled so LDS holds chunk (c ^ ((r>>1)&3))
    const int s0 = tid, s1 = tid + 256;
    const int r0 = s0 >> 2, c0 = (s0 & 3) ^ ((r0 >> 1) & 3);
    const int r1 = s1 >> 2, c1 = (s1 & 3) ^ ((r1 >> 1) & 3);

    const short* aSrc0 = A + (brow + (size_t)r0) * IN_DIM + c0 * 8;
    const short* aSrc1 = A + (brow + (size_t)r1) * IN_DIM + c1 * 8;
    const short* bSrc0 = B + (bcol + (size_t)r0) * IN_DIM + c0 * 8;
    const short* bSrc1 = B + (bcol + (size_t)r1) * IN_DIM + c1 * 8;

    short* lA0 = lsA + s0 * 8;
    short* lA1 = lsA + s1 * 8;
    short* lB0 = lsB + s0 * 8;
    short* lB1 = lsB + s1 * 8;

    // fragment read addresses (k-invariant, hoisted)
    const int frow = lane & 15;       // row within 16x16 frag
    const int kc   = lane >> 4;       // k-chunk 0..3 (8 bf16 each)
    int aOff[4], bOff[4];
    #pragma unroll
    for (int m = 0; m < 4; ++m) {
        int row = wr * 64 + m * 16 + frow;
        int ch  = kc ^ ((row >> 1) & 3);
        aOff[m] = row * BK + ch * 8;
    }
    #pragma unroll
    for (int n = 0; n < 4; ++n) {
        int row = wc * 64 + n * 16 + frow;
        int ch  = kc ^ ((row >> 1) & 3);
        bOff[n] = row * BK + ch * 8;
    }

    f32x4 acc[4][4] = {};

    for (int k0 = 0; k0 < IN_DIM; k0 += BK) {
        GLOAD16(aSrc0 + k0, lA0);
        GLOAD16(aSrc1 + k0, lA1);
        GLOAD16(bSrc0 + k0, lB0);
        GLOAD16(bSrc1 + k0, lB1);
        __syncthreads();   // compiler drains vmcnt before s_barrier

        bf16x8 af[4], bfr[4];
        #pragma unroll
        for (int m = 0; m < 4; ++m) af[m]  = *(const bf16x8*)(lsA + aOff[m]);
        #pragma unroll
        for (int n = 0; n < 4; ++n) bfr[n] = *(const bf16x8*)(lsB + bOff[n]);

        #pragma unroll
        for (int m = 0; m < 4; ++m)
            #pragma unroll
            for (int n = 0; n < 4; ++n)
                acc[m][n] = __builtin_amdgcn_mfma_f32_16x16x32_bf16(
                    af[m], bfr[n], acc[m][n], 0, 0, 0);

        __syncthreads();
    }

    // epilogue: C/D layout col = lane&15, row = (lane>>4)*4 + reg
    #pragma unroll
    for (int n = 0; n < 4; ++n) {
        const int col = (int)bcol + wc * 64 + n * 16 + (lane & 15);
        const float bv = bias[col];
        #pragma unroll
        for (int m = 0; m < 4; ++m) {
            const size_t row0 = brow + wr * 64 + m * 16 + (lane >> 4) * 4;
            #pragma unroll
            for (int r = 0; r < 4; ++r) {
                C[(row0 + r) * OUT_DIM + col] = acc[m][n][r] + bv;
            }
        }
    }
}

// ---------------------------------------------------------------------------
extern "C" void kernel_launch(void* const* d_in, const int* in_sizes, int n_in,
                              void* d_out, int out_size, void* d_ws, size_t ws_size,
                              hipStream_t stream)
{
    const float* x        = (const float*)d_in[0];  // [4,2048,4096] fp32
    const float* norms_p  = (const float*)d_in[1];  // [4096,32]
    const float* norms_r  = (const float*)d_in[2];  // [4096,32]
    const float* bias     = (const float*)d_in[3];  // [4096]
    const int*   idx_p    = (const int*)d_in[4];    // [4096,32,128]
    const int*   idx_r    = (const int*)d_in[5];    // [4096,32,128]
    float*       out      = (float*)d_out;          // [4,2048,4096] fp32

    // workspace: xb (64 MB) | W (32 MB)  -- requires ws_size >= 96 MB
    short* xb = (short*)d_ws;                            // [M][K] bf16
    short* wq = (short*)d_ws + (size_t)M_TOTAL * IN_DIM; // [N][K] bf16

    // 1) dequantize weights: one wave per (o, g) -> 4096*32 waves
    dequant_kernel<<<(OUT_DIM * NGROUPS) / 4, 256, 0, stream>>>(
        norms_p, norms_r, idx_p, idx_r, wq);

    // 2) cast x to bf16
    cast_kernel<<<(int)(((size_t)M_TOTAL * IN_DIM) / (256 * 8)), 256, 0, stream>>>(x, xb);

    // 3) GEMM + bias
    gemm_kernel<<<(M_TOTAL / BM) * (OUT_DIM / BN), 256, 0, stream>>>(xb, wq, bias, out);
}

// Round 2
// 303.317 us; speedup vs baseline: 1.3188x; 1.3188x over previous
//
#include <hip/hip_runtime.h>
#include <hip/hip_bf16.h>
#include <stdint.h>

// Problem constants
#define OUT_DIM 4096
#define IN_DIM  4096
#define GROUPSZ 128
#define NGROUPS 32
#define M_TOTAL 8192   // 4 * 2048
#define EPS_Q   1e-12f

// GEMM tiling: 256x256 tile, BK=32, quad-buffered LDS, 8 waves (2Mx4N)
#define BM 256
#define BN 256
#define BK 32
#define NT (IN_DIM / BK)   // 128 K-tiles

typedef float f32x4   __attribute__((ext_vector_type(4)));
typedef float float4v __attribute__((ext_vector_type(4)));
typedef short bf16x8  __attribute__((ext_vector_type(8)));

// RNE float->bf16
static __device__ __forceinline__ short f2bf(float f) {
    union { float f; unsigned u; } v; v.f = f;
    unsigned r = v.u + 0x7fffu + ((v.u >> 16) & 1u);
    return (short)(r >> 16);
}

// async global->LDS, 16B/lane, linear LDS dest (wave-uniform base + lane*16)
#define GLOAD16(gp, lp) __builtin_amdgcn_global_load_lds( \
    (const __attribute__((address_space(1))) void*)(gp),  \
    (__attribute__((address_space(3))) void*)(lp), 16, 0, 0)

// ---------------------------------------------------------------------------
// Kernel 1: dequantize W (bf16, [N][K] = B^T layout). One wave per (o, g).
// ---------------------------------------------------------------------------
__global__ __launch_bounds__(256) void dequant_kernel(
    const float* __restrict__ norms_p, const float* __restrict__ norms_r,
    const int* __restrict__ idx_p, const int* __restrict__ idx_r,
    short* __restrict__ W)
{
    const int gid  = (int)((blockIdx.x * 256u + threadIdx.x) >> 6);
    const int lane = threadIdx.x & 63;
    const size_t base = (size_t)gid * GROUPSZ;

    const int ip0 = idx_p[base + lane];
    const int ip1 = idx_p[base + lane + 64];
    const int ir0 = idx_r[base + lane];
    const int ir1 = idx_r[base + lane + 64];

    const float qp0 = -1.f + (2.f / 15.f) * (float)ip0;
    const float qp1 = -1.f + (2.f / 15.f) * (float)ip1;
    const float qr0 = -1.f + (2.f / 3.f)  * (float)ir0;
    const float qr1 = -1.f + (2.f / 3.f)  * (float)ir1;

    float ssp = qp0 * qp0 + qp1 * qp1;
    float ssr = qr0 * qr0 + qr1 * qr1;
    #pragma unroll
    for (int m = 32; m >= 1; m >>= 1) {
        ssp += __shfl_xor(ssp, m);
        ssr += __shfl_xor(ssr, m);
    }
    const float sp = norms_p[gid] / sqrtf(ssp + EPS_Q);
    const float sr = norms_r[gid] / sqrtf(ssr + EPS_Q);

    W[base + lane]      = f2bf(qp0 * sp + qr0 * sr);
    W[base + lane + 64] = f2bf(qp1 * sp + qr1 * sr);
}

// ---------------------------------------------------------------------------
// Kernel 2: x fp32 -> bf16, 8 elems/thread
// ---------------------------------------------------------------------------
__global__ __launch_bounds__(256) void cast_kernel(
    const float* __restrict__ x, short* __restrict__ xb)
{
    const size_t i = ((size_t)blockIdx.x * 256u + threadIdx.x) * 8u;
    float4v a = *(const float4v*)(x + i);
    float4v b = *(const float4v*)(x + i + 4);
    bf16x8 o;
    o[0] = f2bf(a[0]); o[1] = f2bf(a[1]); o[2] = f2bf(a[2]); o[3] = f2bf(a[3]);
    o[4] = f2bf(b[0]); o[5] = f2bf(b[1]); o[6] = f2bf(b[2]); o[7] = f2bf(b[3]);
    *(bf16x8*)(xb + i) = o;
}

// ---------------------------------------------------------------------------
// Kernel 3: C[M][N] = A[M][K] @ B[N][K]^T + bias
// 256x256 tile, BK=32, quad-buffered LDS, counted vmcnt (never 0 in loop),
// one raw s_barrier per K-tile, setprio around MFMA cluster.
// ---------------------------------------------------------------------------
__global__ __launch_bounds__(512, 2) void gemm_kernel(
    const short* __restrict__ A,   // [M][K] bf16
    const short* __restrict__ B,   // [N][K] bf16
    const float* __restrict__ bias,
    float* __restrict__ C)
{
    // A bufs: [0, 32768) shorts (4 x 8192); B bufs: [32768, 65536)
    __shared__ short lds[65536];   // 128 KiB

    const int tid  = threadIdx.x;
    const int lane = tid & 63;
    const int wid  = tid >> 6;     // 0..7
    const int wr   = wid >> 2;     // 0..1 (M)
    const int wc   = wid & 3;      // 0..3 (N)

    // bijective XCD swizzle (nwg = 512, divisible by 8)
    const int nwg = gridDim.x;
    const int cpx = nwg >> 3;
    const int wg  = ((int)blockIdx.x & 7) * cpx + ((int)blockIdx.x >> 3);
    const int ntile = wg & 15;             // N/BN = 16
    const int mtile = wg >> 4;             // M/BM = 32
    const size_t brow = (size_t)mtile * BM;
    const size_t bcol = (size_t)ntile * BN;

    // staging slots: s in [0,1024): row r = s>>2, chunk c = s&3 (16B chunks)
    // LDS linear; global source pre-swizzled: chunk ^= (row>>1)&3
    const int s0 = tid, s1 = tid + 512;
    const int r0 = s0 >> 2, c0 = (s0 & 3) ^ ((r0 >> 1) & 3);
    const int r1 = s1 >> 2, c1 = (s1 & 3) ^ ((r1 >> 1) & 3);

    const short* aG0 = A + (brow + (size_t)r0) * IN_DIM + c0 * 8;
    const short* aG1 = A + (brow + (size_t)r1) * IN_DIM + c1 * 8;
    const short* bG0 = B + (bcol + (size_t)r0) * IN_DIM + c0 * 8;
    const short* bG1 = B + (bcol + (size_t)r1) * IN_DIM + c1 * 8;

    short* ldA0 = lds + s0 * 8;
    short* ldA1 = lds + s1 * 8;
    short* ldB0 = lds + 32768 + s0 * 8;
    short* ldB1 = lds + 32768 + s1 * 8;

    // fragment read bases (swizzled): row*32 + (kc ^ ((row>>1)&3))*8 shorts
    const int fr   = lane & 15;
    const int kc   = lane >> 4;
    const int xorc = kc ^ ((fr >> 1) & 3);   // m*16 / n*16 row steps don't change the xor
    const int aBase = wr * 4096 + fr * 32 + xorc * 8;            // + m*512
    const int bBase = 32768 + wc * 2048 + fr * 32 + xorc * 8;    // + n*512

    f32x4 acc[8][4] = {};

    auto stage = [&](int t) {
        const int boff = (t & 3) * 8192;
        const int ko   = t * BK;
        GLOAD16(aG0 + ko, ldA0 + boff);
        GLOAD16(aG1 + ko, ldA1 + boff);
        GLOAD16(bG0 + ko, ldB0 + boff);
        GLOAD16(bG1 + ko, ldB1 + boff);
    };

    auto compute = [&](int t) {
        const short* pA = lds + (t & 3) * 8192 + aBase;
        const short* pB = lds + (t & 3) * 8192 + bBase;
        bf16x8 af[8], bf[4];
        #pragma unroll
        for (int m = 0; m < 8; ++m) af[m] = *(const bf16x8*)(pA + m * 512);
        #pragma unroll
        for (int n = 0; n < 4; ++n) bf[n] = *(const bf16x8*)(pB + n * 512);
        __builtin_amdgcn_s_setprio(1);
        #pragma unroll
        for (int m = 0; m < 8; ++m)
            #pragma unroll
            for (int n = 0; n < 4; ++n)
                acc[m][n] = __builtin_amdgcn_mfma_f32_16x16x32_bf16(
                    af[m], bf[n], acc[m][n], 0, 0, 0);
        __builtin_amdgcn_s_setprio(0);
    };

    // prologue: 3 K-tiles in flight (12 loads)
    stage(0); stage(1); stage(2);

    // main loop: wait tile t (keep tiles t+1,t+2 = 8 loads in flight across
    // the barrier), then prefetch t+3 and compute t. Single barrier per tile:
    // passing it proves every wave finished its ds_reads of tile t-1 (data
    // dep through MFMA forces lgkmcnt), so buf[(t+3)&3] is free to overwrite.
    #pragma unroll 1
    for (int t = 0; t < NT - 3; ++t) {
        asm volatile("s_waitcnt vmcnt(8)" ::: "memory");
        __builtin_amdgcn_s_barrier();
        __builtin_amdgcn_sched_barrier(0);
        stage(t + 3);
        compute(t);
    }
    // tail: tiles NT-3, NT-2, NT-1 already staged
    asm volatile("s_waitcnt vmcnt(8)" ::: "memory");
    __builtin_amdgcn_s_barrier();
    __builtin_amdgcn_sched_barrier(0);
    compute(NT - 3);
    asm volatile("s_waitcnt vmcnt(4)" ::: "memory");
    __builtin_amdgcn_s_barrier();
    __builtin_amdgcn_sched_barrier(0);
    compute(NT - 2);
    asm volatile("s_waitcnt vmcnt(0)" ::: "memory");
    __builtin_amdgcn_s_barrier();
    __builtin_amdgcn_sched_barrier(0);
    compute(NT - 1);

    // epilogue: C/D layout col = lane&15, row = (lane>>4)*4 + reg
    #pragma unroll
    for (int n = 0; n < 4; ++n) {
        const int col = (int)bcol + wc * 64 + n * 16 + fr;
        const float bv = bias[col];
        #pragma unroll
        for (int m = 0; m < 8; ++m) {
            const size_t row0 = brow + wr * 128 + m * 16 + kc * 4;
            #pragma unroll
            for (int r = 0; r < 4; ++r)
                C[(row0 + r) * OUT_DIM + col] = acc[m][n][r] + bv;
        }
    }
}

// ---------------------------------------------------------------------------
extern "C" void kernel_launch(void* const* d_in, const int* in_sizes, int n_in,
                              void* d_out, int out_size, void* d_ws, size_t ws_size,
                              hipStream_t stream)
{
    const float* x        = (const float*)d_in[0];
    const float* norms_p  = (const float*)d_in[1];
    const float* norms_r  = (const float*)d_in[2];
    const float* bias     = (const float*)d_in[3];
    const int*   idx_p    = (const int*)d_in[4];
    const int*   idx_r    = (const int*)d_in[5];
    float*       out      = (float*)d_out;

    // workspace: xb (64 MB bf16 [M][K]) | W (32 MB bf16 [N][K])
    short* xb = (short*)d_ws;
    short* wq = (short*)d_ws + (size_t)M_TOTAL * IN_DIM;

    dequant_kernel<<<(OUT_DIM * NGROUPS) / 4, 256, 0, stream>>>(
        norms_p, norms_r, idx_p, idx_r, wq);

    cast_kernel<<<(int)(((size_t)M_TOTAL * IN_DIM) / (256 * 8)), 256, 0, stream>>>(x, xb);

    gemm_kernel<<<(M_TOTAL / BM) * (OUT_DIM / BN), 512, 0, stream>>>(xb, wq, bias, out);
}

// Round 3
// 292.753 us; speedup vs baseline: 1.3664x; 1.0361x over previous
//
#include <hip/hip_runtime.h>
#include <hip/hip_bf16.h>
#include <stdint.h>

// Problem constants
#define OUT_DIM 4096
#define IN_DIM  4096
#define GROUPSZ 128
#define NGROUPS 32
#define M_TOTAL 8192   // 4 * 2048
#define EPS_Q   1e-12f

// GEMM tiling: 256x256 tile, BK=64, 8 waves (2M x 4N), 8-phase schedule
#define BM 256
#define BN 256
#define BK 64
#define NT (IN_DIM / BK)   // 64 K-tiles

typedef float f32x4   __attribute__((ext_vector_type(4)));
typedef float float4v __attribute__((ext_vector_type(4)));
typedef short bf16x8  __attribute__((ext_vector_type(8)));

static __device__ __forceinline__ short f2bf(float f) {
    union { float f; unsigned u; } v; v.f = f;
    unsigned r = v.u + 0x7fffu + ((v.u >> 16) & 1u);
    return (short)(r >> 16);
}

#define GLOAD16(gp, lp) __builtin_amdgcn_global_load_lds( \
    (const __attribute__((address_space(1))) void*)(gp),  \
    (__attribute__((address_space(3))) void*)(lp), 16, 0, 0)

// ---------------------------------------------------------------------------
// Kernel 1: dequantize W (bf16, [N][K] = B^T layout). One wave per (o, g).
// ---------------------------------------------------------------------------
__global__ __launch_bounds__(256) void dequant_kernel(
    const float* __restrict__ norms_p, const float* __restrict__ norms_r,
    const int* __restrict__ idx_p, const int* __restrict__ idx_r,
    short* __restrict__ W)
{
    const int gid  = (int)((blockIdx.x * 256u + threadIdx.x) >> 6);
    const int lane = threadIdx.x & 63;
    const size_t base = (size_t)gid * GROUPSZ;

    const int ip0 = idx_p[base + lane];
    const int ip1 = idx_p[base + lane + 64];
    const int ir0 = idx_r[base + lane];
    const int ir1 = idx_r[base + lane + 64];

    const float qp0 = -1.f + (2.f / 15.f) * (float)ip0;
    const float qp1 = -1.f + (2.f / 15.f) * (float)ip1;
    const float qr0 = -1.f + (2.f / 3.f)  * (float)ir0;
    const float qr1 = -1.f + (2.f / 3.f)  * (float)ir1;

    float ssp = qp0 * qp0 + qp1 * qp1;
    float ssr = qr0 * qr0 + qr1 * qr1;
    #pragma unroll
    for (int m = 32; m >= 1; m >>= 1) {
        ssp += __shfl_xor(ssp, m);
        ssr += __shfl_xor(ssr, m);
    }
    const float sp = norms_p[gid] / sqrtf(ssp + EPS_Q);
    const float sr = norms_r[gid] / sqrtf(ssr + EPS_Q);

    W[base + lane]      = f2bf(qp0 * sp + qr0 * sr);
    W[base + lane + 64] = f2bf(qp1 * sp + qr1 * sr);
}

// ---------------------------------------------------------------------------
// Kernel 2: x fp32 -> bf16, 8 elems/thread
// ---------------------------------------------------------------------------
__global__ __launch_bounds__(256) void cast_kernel(
    const float* __restrict__ x, short* __restrict__ xb)
{
    const size_t i = ((size_t)blockIdx.x * 256u + threadIdx.x) * 8u;
    float4v a = *(const float4v*)(x + i);
    float4v b = *(const float4v*)(x + i + 4);
    bf16x8 o;
    o[0] = f2bf(a[0]); o[1] = f2bf(a[1]); o[2] = f2bf(a[2]); o[3] = f2bf(a[3]);
    o[4] = f2bf(b[0]); o[5] = f2bf(b[1]); o[6] = f2bf(b[2]); o[7] = f2bf(b[3]);
    *(bf16x8*)(xb + i) = o;
}

// ---------------------------------------------------------------------------
// GEMM helpers (compile-time indexed everywhere — rule #20)
// ---------------------------------------------------------------------------
template<int HA, int HB>
__device__ __forceinline__ void mfma_quad(f32x4 (&acc)[2][2][4][2],
                                          const bf16x8 (&af)[4][2],
                                          const bf16x8 (&bf)[2][2]) {
#pragma unroll
    for (int m = 0; m < 4; ++m)
#pragma unroll
        for (int n = 0; n < 2; ++n)
#pragma unroll
            for (int kh = 0; kh < 2; ++kh)
                acc[HA][HB][m][n] = __builtin_amdgcn_mfma_f32_16x16x32_bf16(
                    af[m][kh], bf[n][kh], acc[HA][HB][m][n], 0, 0, 0);
}

static __device__ __forceinline__ void rd8(const short* base, int ck0, int ck1,
                                           bf16x8 (&f)[4][2]) {
#pragma unroll
    for (int m = 0; m < 4; ++m) {
        f[m][0] = *(const bf16x8*)(base + m * 1024 + ck0);
        f[m][1] = *(const bf16x8*)(base + m * 1024 + ck1);
    }
}

static __device__ __forceinline__ void rd4(const short* base, int ck0, int ck1,
                                           bf16x8 (&f)[2][2]) {
#pragma unroll
    for (int n = 0; n < 2; ++n) {
        f[n][0] = *(const bf16x8*)(base + n * 1024 + ck0);
        f[n][1] = *(const bf16x8*)(base + n * 1024 + ck1);
    }
}

#define BARRIER()  asm volatile("s_barrier" ::: "memory")
#define LGKM0()    do { asm volatile("s_waitcnt lgkmcnt(0)" ::: "memory"); \
                        __builtin_amdgcn_sched_barrier(0); } while (0)
#define WAITV(N)   asm volatile("s_waitcnt vmcnt(" #N ")" ::: "memory")

// ---------------------------------------------------------------------------
// Kernel 3: C[M][N] = A[M][K] @ B[N][K]^T + bias, bf16 in / fp32 out.
// 256x256 tile, BK=64. 4 phases per K-tile; phase p computes C-quadrant
// (A-half p>>1, B-half p&1) — every wave reads the SAME halves each phase,
// so halves release early and staging runs 5-6 phases ahead:
//   tile t stages: p0:(t+1).A1  p1:(t+1).B1  p2:(t+2).A0  p3:(t+2).B0
// Waits (2 loads per half): end-p0 vmcnt(6) lands (t)A1,(t)B1;
//                           end-p3 vmcnt(8) lands (t+1)A0,(t+1)B0.
// LDS 128 KiB: parity*32768 + {A0:0, A1:8192, B0:16384, B1:24576} shorts.
// Chunk swizzle: LDS chunk = global_chunk ^ (row&7) (both-sides involution).
// ---------------------------------------------------------------------------
__global__ __launch_bounds__(512, 2) void gemm_kernel(
    const short* __restrict__ Ag,  // [M][K] bf16
    const short* __restrict__ Bg,  // [N][K] bf16
    const float* __restrict__ bias,
    float* __restrict__ C)
{
    __shared__ short lds[65536];   // 128 KiB

    const int tid  = threadIdx.x;
    const int lane = tid & 63;
    const int wid  = tid >> 6;     // 0..7
    const int wr   = wid >> 2;     // 0..1 (M)
    const int wc   = wid & 3;      // 0..3 (N)
    const int fr   = lane & 15;
    const int lq   = lane >> 4;    // 0..3

    // bijective XCD swizzle (nwg = 512, divisible by 8)
    const int nwg = gridDim.x;
    const int cpx = nwg >> 3;
    const int wg  = ((int)blockIdx.x & 7) * cpx + ((int)blockIdx.x >> 3);
    const int ntile = wg & 15;              // N/BN = 16
    const int mtile = wg >> 4;              // M/BM = 32
    const uint32_t brow = (uint32_t)mtile * BM;
    const uint32_t bcol = (uint32_t)ntile * BN;

    // staging: slot s (0..1023): row r = s>>3, chunk c = s&7; thread owns
    // s = tid and s = tid+512. global chunk = c ^ (r&7).
    const uint32_t sr_ = (uint32_t)(tid >> 3);
    const uint32_t gc_ = (uint32_t)((tid & 7) ^ ((tid >> 3) & 7));
    const uint32_t aOffB = (brow + sr_) * IN_DIM + gc_ * 8;  // slot tid; +262144 for slot tid+512
    const uint32_t bOffB = (bcol + sr_) * IN_DIM + gc_ * 8;

    auto stage = [&](const short* M, uint32_t baseOff, uint32_t extra, short* dstRegion) {
        GLOAD16(M + baseOff + extra,            dstRegion + tid * 8);
        GLOAD16(M + baseOff + extra + 262144u,  dstRegion + tid * 8 + 4096);
    };

    // fragment read offsets (shorts): row*64 + ((kh*4+kc)^(fr&7))*8
    const int c0  = (lq ^ (fr & 7));
    const int ck0 = c0 * 8;
    const int ck1 = (c0 ^ 4) * 8;
    const int aRd = (wr * 64 + fr) * 64;
    const int bRd = (wc * 32 + fr) * 64;

    f32x4  acc[2][2][4][2] = {};
    bf16x8 af[4][2], bf0[2][2], bf1[2][2];

    // prologue: (0)A0,(0)B0,(0)A1,(0)B1,(1)A0,(1)B0 = 12 loads
    stage(Ag, aOffB, 0u,            lds);
    stage(Bg, bOffB, 0u,            lds + 16384);
    stage(Ag, aOffB, 524288u,       lds + 8192);
    stage(Bg, bOffB, 524288u,       lds + 24576);
    stage(Ag, aOffB, 64u,           lds + 32768);
    stage(Bg, bOffB, 64u,           lds + 32768 + 16384);
    WAITV(8);          // (0)A0,(0)B0 landed
    BARRIER();

#define TILE_BODY(T, STG0, STG1, STG2, STG3, WAIT_P0, WAIT_P3) do {           \
    short* sb = lds + (((T) & 1) ? 32768 : 0);                                \
    short* ob = lds + (((T) & 1) ? 0 : 32768);                                \
    /* phase 0: quad (A0,B0) */                                               \
    rd8(sb + aRd, ck0, ck1, af);                                              \
    rd4(sb + 16384 + bRd, ck0, ck1, bf0);                                     \
    if (STG0) stage(Ag, aOffB, 524288u + (uint32_t)((T) + 1) * 64u, ob + 8192); \
    BARRIER(); LGKM0();                                                       \
    __builtin_amdgcn_s_setprio(1); mfma_quad<0,0>(acc, af, bf0);              \
    __builtin_amdgcn_s_setprio(0);                                            \
    WAIT_P0;                                                                  \
    BARRIER();                                                                \
    /* phase 1: quad (A0,B1) */                                               \
    rd4(sb + 24576 + bRd, ck0, ck1, bf1);                                     \
    if (STG1) stage(Bg, bOffB, 524288u + (uint32_t)((T) + 1) * 64u, ob + 24576); \
    BARRIER(); LGKM0();                                                       \
    __builtin_amdgcn_s_setprio(1); mfma_quad<0,1>(acc, af, bf1);              \
    __builtin_amdgcn_s_setprio(0);                                            \
    BARRIER();                                                                \
    /* phase 2: quad (A1,B0) */                                               \
    rd8(sb + 8192 + aRd, ck0, ck1, af);                                       \
    if (STG2) stage(Ag, aOffB, (uint32_t)((T) + 2) * 64u, sb);                \
    BARRIER(); LGKM0();                                                       \
    __builtin_amdgcn_s_setprio(1); mfma_quad<1,0>(acc, af, bf0);              \
    __builtin_amdgcn_s_setprio(0);                                            \
    BARRIER();                                                                \
    /* phase 3: quad (A1,B1) */                                               \
    if (STG3) stage(Bg, bOffB, (uint32_t)((T) + 2) * 64u, sb + 16384);        \
    BARRIER(); LGKM0();                                                       \
    __builtin_amdgcn_s_setprio(1); mfma_quad<1,1>(acc, af, bf1);              \
    __builtin_amdgcn_s_setprio(0);                                            \
    WAIT_P3;                                                                  \
    BARRIER();                                                                \
} while (0)

    #pragma unroll 1
    for (int t = 0; t < NT - 2; ++t) {
        TILE_BODY(t, 1, 1, 1, 1, WAITV(6), WAITV(8));
    }
    TILE_BODY(NT - 2, 1, 1, 0, 0, WAITV(6), WAITV(4));
    TILE_BODY(NT - 1, 0, 0, 0, 0, WAITV(0), (void)0);

    // epilogue: C/D layout col = lane&15, row = lq*4 + reg
    #pragma unroll
    for (int hA = 0; hA < 2; ++hA)
    #pragma unroll
    for (int hB = 0; hB < 2; ++hB)
    #pragma unroll
    for (int n = 0; n < 2; ++n) {
        const int col = (int)bcol + hB * 128 + wc * 32 + n * 16 + fr;
        const float bv = bias[col];
        #pragma unroll
        for (int m = 0; m < 4; ++m) {
            const size_t row0 = (size_t)brow + hA * 128 + wr * 64 + m * 16 + lq * 4;
            #pragma unroll
            for (int r = 0; r < 4; ++r)
                C[(row0 + r) * OUT_DIM + col] = acc[hA][hB][m][n][r] + bv;
        }
    }
#undef TILE_BODY
}

// ---------------------------------------------------------------------------
extern "C" void kernel_launch(void* const* d_in, const int* in_sizes, int n_in,
                              void* d_out, int out_size, void* d_ws, size_t ws_size,
                              hipStream_t stream)
{
    const float* x        = (const float*)d_in[0];
    const float* norms_p  = (const float*)d_in[1];
    const float* norms_r  = (const float*)d_in[2];
    const float* bias     = (const float*)d_in[3];
    const int*   idx_p    = (const int*)d_in[4];
    const int*   idx_r    = (const int*)d_in[5];
    float*       out      = (float*)d_out;

    // workspace: xb (64 MB bf16 [M][K]) | W (32 MB bf16 [N][K])
    short* xb = (short*)d_ws;
    short* wq = (short*)d_ws + (size_t)M_TOTAL * IN_DIM;

    dequant_kernel<<<(OUT_DIM * NGROUPS) / 4, 256, 0, stream>>>(
        norms_p, norms_r, idx_p, idx_r, wq);

    cast_kernel<<<(int)(((size_t)M_TOTAL * IN_DIM) / (256 * 8)), 256, 0, stream>>>(x, xb);

    gemm_kernel<<<(M_TOTAL / BM) * (OUT_DIM / BN), 512, 0, stream>>>(xb, wq, bias, out);
}

// Round 4
// 281.227 us; speedup vs baseline: 1.4224x; 1.0410x over previous
//
#include <hip/hip_runtime.h>
#include <hip/hip_bf16.h>
#include <stdint.h>

// Problem constants
#define OUT_DIM 4096
#define IN_DIM  4096
#define GROUPSZ 128
#define NGROUPS 32
#define M_TOTAL 8192   // 4 * 2048
#define EPS_Q   1e-12f

// GEMM tiling: 256x256 tile, BK=64, 8 waves (2M x 4N)
#define BM 256
#define BN 256
#define BK 64
#define NT (IN_DIM / BK)   // 64 K-tiles

typedef float f32x4   __attribute__((ext_vector_type(4)));
typedef float float4v __attribute__((ext_vector_type(4)));
typedef short bf16x8  __attribute__((ext_vector_type(8)));

static __device__ __forceinline__ short f2bf(float f) {
    union { float f; unsigned u; } v; v.f = f;
    unsigned r = v.u + 0x7fffu + ((v.u >> 16) & 1u);
    return (short)(r >> 16);
}

#define GLOAD16(gp, lp) __builtin_amdgcn_global_load_lds( \
    (const __attribute__((address_space(1))) void*)(gp),  \
    (__attribute__((address_space(3))) void*)(lp), 16, 0, 0)

// ---------------------------------------------------------------------------
// Kernel 1: dequantize W (bf16, [N][K] = B^T layout). One wave per (o, g).
// ---------------------------------------------------------------------------
__global__ __launch_bounds__(256) void dequant_kernel(
    const float* __restrict__ norms_p, const float* __restrict__ norms_r,
    const int* __restrict__ idx_p, const int* __restrict__ idx_r,
    short* __restrict__ W)
{
    const int gid  = (int)((blockIdx.x * 256u + threadIdx.x) >> 6);
    const int lane = threadIdx.x & 63;
    const size_t base = (size_t)gid * GROUPSZ;

    const int ip0 = idx_p[base + lane];
    const int ip1 = idx_p[base + lane + 64];
    const int ir0 = idx_r[base + lane];
    const int ir1 = idx_r[base + lane + 64];

    const float qp0 = -1.f + (2.f / 15.f) * (float)ip0;
    const float qp1 = -1.f + (2.f / 15.f) * (float)ip1;
    const float qr0 = -1.f + (2.f / 3.f)  * (float)ir0;
    const float qr1 = -1.f + (2.f / 3.f)  * (float)ir1;

    float ssp = qp0 * qp0 + qp1 * qp1;
    float ssr = qr0 * qr0 + qr1 * qr1;
    #pragma unroll
    for (int m = 32; m >= 1; m >>= 1) {
        ssp += __shfl_xor(ssp, m);
        ssr += __shfl_xor(ssr, m);
    }
    const float sp = norms_p[gid] / sqrtf(ssp + EPS_Q);
    const float sr = norms_r[gid] / sqrtf(ssr + EPS_Q);

    W[base + lane]      = f2bf(qp0 * sp + qr0 * sr);
    W[base + lane + 64] = f2bf(qp1 * sp + qr1 * sr);
}

// ---------------------------------------------------------------------------
// Kernel 2: x fp32 -> bf16, 8 elems/thread
// ---------------------------------------------------------------------------
__global__ __launch_bounds__(256) void cast_kernel(
    const float* __restrict__ x, short* __restrict__ xb)
{
    const size_t i = ((size_t)blockIdx.x * 256u + threadIdx.x) * 8u;
    float4v a = *(const float4v*)(x + i);
    float4v b = *(const float4v*)(x + i + 4);
    bf16x8 o;
    o[0] = f2bf(a[0]); o[1] = f2bf(a[1]); o[2] = f2bf(a[2]); o[3] = f2bf(a[3]);
    o[4] = f2bf(b[0]); o[5] = f2bf(b[1]); o[6] = f2bf(b[2]); o[7] = f2bf(b[3]);
    *(bf16x8*)(xb + i) = o;
}

// ---------------------------------------------------------------------------
// GEMM helpers (compile-time indexed everywhere — rule #20)
// ---------------------------------------------------------------------------
template<int HA, int HB>
__device__ __forceinline__ void mfma_quad(f32x4 (&acc)[2][2][4][2],
                                          const bf16x8 (&af)[4][2],
                                          const bf16x8 (&bf)[2][2]) {
#pragma unroll
    for (int m = 0; m < 4; ++m)
#pragma unroll
        for (int n = 0; n < 2; ++n)
#pragma unroll
            for (int kh = 0; kh < 2; ++kh)
                acc[HA][HB][m][n] = __builtin_amdgcn_mfma_f32_16x16x32_bf16(
                    af[m][kh], bf[n][kh], acc[HA][HB][m][n], 0, 0, 0);
}

static __device__ __forceinline__ void rd8(const short* base, int ck0, int ck1,
                                           bf16x8 (&f)[4][2]) {
#pragma unroll
    for (int m = 0; m < 4; ++m) {
        f[m][0] = *(const bf16x8*)(base + m * 1024 + ck0);
        f[m][1] = *(const bf16x8*)(base + m * 1024 + ck1);
    }
}

static __device__ __forceinline__ void rd4(const short* base, int ck0, int ck1,
                                           bf16x8 (&f)[2][2]) {
#pragma unroll
    for (int n = 0; n < 2; ++n) {
        f[n][0] = *(const bf16x8*)(base + n * 1024 + ck0);
        f[n][1] = *(const bf16x8*)(base + n * 1024 + ck1);
    }
}

#define BARRIER()  asm volatile("s_barrier" ::: "memory")
#define SCHEDBAR() __builtin_amdgcn_sched_barrier(0)
#define LGKMC(N)   do { asm volatile("s_waitcnt lgkmcnt(" #N ")" ::: "memory"); \
                        SCHEDBAR(); } while (0)
#define WAITV(N)   asm volatile("s_waitcnt vmcnt(" #N ")" ::: "memory")

// ---------------------------------------------------------------------------
// Kernel 3: C[M][N] = A[M][K] @ B[N][K]^T + bias, bf16 in / fp32 out.
// 256x256 tile, BK=64. Per K-tile, 4 MFMA quads (C-quadrants), only TWO
// barriers (minimal hazard set) and counted lgkm waits:
//   [entry: A0,B0 of t landed (prev tile's vmcnt(8)+barrier)]
//   batch1: rd A0(8)+B0(4); stage (t+1)A1; lgkmcnt(0); MFMA(0,0)
//   WAITV(6); BARRIER            // lands (t)A1,(t)B1; releases A0/B0 regions
//   batch2: rd B1(4) then A1(8); stage (t+1)B1
//   lgkmcnt(8)  -> MFMA(0,1)     // waits only B1; A1 reads still in flight
//   stage (t+2)A0
//   lgkmcnt(0)  -> MFMA(1,0)     // A1 landed under MFMA(0,1)
//   stage (t+2)B0
//   MFMA(1,1)
//   WAITV(8); BARRIER            // lands (t+1)A0,B0
// Hazards: every stage-write region's readers completed at their own lgkmcnt
// before one of the two barriers separating read from write (checked per
// region; same vmcnt ledger as round 3, which validated).
// LDS 128 KiB: parity*32768 + {A0:0, A1:8192, B0:16384, B1:24576} shorts.
// Chunk swizzle: LDS chunk = global_chunk ^ (row&7) (both-sides involution).
// ---------------------------------------------------------------------------
__global__ __launch_bounds__(512, 2) void gemm_kernel(
    const short* __restrict__ Ag,  // [M][K] bf16
    const short* __restrict__ Bg,  // [N][K] bf16
    const float* __restrict__ bias,
    float* __restrict__ C)
{
    __shared__ short lds[65536];   // 128 KiB

    const int tid  = threadIdx.x;
    const int lane = tid & 63;
    const int wid  = tid >> 6;     // 0..7
    const int wr   = wid >> 2;     // 0..1 (M)
    const int wc   = wid & 3;      // 0..3 (N)
    const int fr   = lane & 15;
    const int lq   = lane >> 4;    // 0..3

    // bijective XCD swizzle (nwg = 512, divisible by 8)
    const int nwg = gridDim.x;
    const int cpx = nwg >> 3;
    const int wg  = ((int)blockIdx.x & 7) * cpx + ((int)blockIdx.x >> 3);
    const int ntile = wg & 15;              // N/BN = 16
    const int mtile = wg >> 4;              // M/BM = 32
    const uint32_t brow = (uint32_t)mtile * BM;
    const uint32_t bcol = (uint32_t)ntile * BN;

    // staging: slot s (0..1023): row r = s>>3, chunk c = s&7; thread owns
    // s = tid and s = tid+512. global chunk = c ^ (r&7).
    const uint32_t sr_ = (uint32_t)(tid >> 3);
    const uint32_t gc_ = (uint32_t)((tid & 7) ^ ((tid >> 3) & 7));
    const uint32_t aOffB = (brow + sr_) * IN_DIM + gc_ * 8;
    const uint32_t bOffB = (bcol + sr_) * IN_DIM + gc_ * 8;

    auto stage = [&](const short* M, uint32_t baseOff, uint32_t extra, short* dstRegion) {
        GLOAD16(M + baseOff + extra,            dstRegion + tid * 8);
        GLOAD16(M + baseOff + extra + 262144u,  dstRegion + tid * 8 + 4096);
    };

    // fragment read offsets (shorts): row*64 + ((kh*4+kc)^(fr&7))*8
    const int c0  = (lq ^ (fr & 7));
    const int ck0 = c0 * 8;
    const int ck1 = (c0 ^ 4) * 8;
    const int aRd = (wr * 64 + fr) * 64;
    const int bRd = (wc * 32 + fr) * 64;

    f32x4  acc[2][2][4][2] = {};
    bf16x8 af[4][2], af2[4][2], bf0[2][2], bf1[2][2];

    // prologue: (0)A0,(0)B0,(0)A1,(0)B1,(1)A0,(1)B0 = 12 loads
    stage(Ag, aOffB, 0u,            lds);
    stage(Bg, bOffB, 0u,            lds + 16384);
    stage(Ag, aOffB, 524288u,       lds + 8192);
    stage(Bg, bOffB, 524288u,       lds + 24576);
    stage(Ag, aOffB, 64u,           lds + 32768);
    stage(Bg, bOffB, 64u,           lds + 32768 + 16384);
    WAITV(8);          // (0)A0,(0)B0 landed; 8 outstanding
    BARRIER();

#define TILE_BODY(T, STG0, STG1, STG2, STG3, WAIT_MID, WAIT_END, BAR_END) do { \
    short* sb = lds + (((T) & 1) ? 32768 : 0);                                \
    short* ob = lds + (((T) & 1) ? 0 : 32768);                                \
    /* batch 1: A0 -> af, B0 -> bf0 (12 ds_reads) */                          \
    rd8(sb + aRd, ck0, ck1, af);                                              \
    rd4(sb + 16384 + bRd, ck0, ck1, bf0);                                     \
    if (STG0) stage(Ag, aOffB, 524288u + (uint32_t)((T) + 1) * 64u, ob + 8192); \
    LGKMC(0);                                                                 \
    __builtin_amdgcn_s_setprio(1); mfma_quad<0,0>(acc, af, bf0);              \
    __builtin_amdgcn_s_setprio(0);                                            \
    WAIT_MID;                                                                 \
    BARRIER();                                                                \
    /* batch 2: B1 -> bf1 (oldest), then A1 -> af2 */                         \
    rd4(sb + 24576 + bRd, ck0, ck1, bf1);                                     \
    SCHEDBAR();                                                               \
    rd8(sb + 8192 + aRd, ck0, ck1, af2);                                      \
    if (STG1) stage(Bg, bOffB, 524288u + (uint32_t)((T) + 1) * 64u, ob + 24576); \
    LGKMC(8);   /* bf1 landed; af2 may still be in flight */                  \
    __builtin_amdgcn_s_setprio(1); mfma_quad<0,1>(acc, af, bf1);              \
    __builtin_amdgcn_s_setprio(0);                                            \
    if (STG2) stage(Ag, aOffB, (uint32_t)((T) + 2) * 64u, sb);                \
    LGKMC(0);   /* af2 landed (covered by MFMA(0,1) issue) */                 \
    __builtin_amdgcn_s_setprio(1); mfma_quad<1,0>(acc, af2, bf0);             \
    __builtin_amdgcn_s_setprio(0);                                            \
    if (STG3) stage(Bg, bOffB, (uint32_t)((T) + 2) * 64u, sb + 16384);        \
    __builtin_amdgcn_s_setprio(1); mfma_quad<1,1>(acc, af2, bf1);             \
    __builtin_amdgcn_s_setprio(0);                                            \
    WAIT_END;                                                                 \
    if (BAR_END) BARRIER();                                                   \
} while (0)

    #pragma unroll 1
    for (int t = 0; t < NT - 2; ++t) {
        TILE_BODY(t, 1, 1, 1, 1, WAITV(6), WAITV(8), 1);
    }
    TILE_BODY(NT - 2, 1, 1, 0, 0, WAITV(6), WAITV(4), 1);
    TILE_BODY(NT - 1, 0, 0, 0, 0, WAITV(0), (void)0, 0);

    // epilogue: C/D layout col = lane&15, row = lq*4 + reg
    #pragma unroll
    for (int hA = 0; hA < 2; ++hA)
    #pragma unroll
    for (int hB = 0; hB < 2; ++hB)
    #pragma unroll
    for (int n = 0; n < 2; ++n) {
        const int col = (int)bcol + hB * 128 + wc * 32 + n * 16 + fr;
        const float bv = bias[col];
        #pragma unroll
        for (int m = 0; m < 4; ++m) {
            const size_t row0 = (size_t)brow + hA * 128 + wr * 64 + m * 16 + lq * 4;
            #pragma unroll
            for (int r = 0; r < 4; ++r)
                C[(row0 + r) * OUT_DIM + col] = acc[hA][hB][m][n][r] + bv;
        }
    }
#undef TILE_BODY
}

// ---------------------------------------------------------------------------
extern "C" void kernel_launch(void* const* d_in, const int* in_sizes, int n_in,
                              void* d_out, int out_size, void* d_ws, size_t ws_size,
                              hipStream_t stream)
{
    const float* x        = (const float*)d_in[0];
    const float* norms_p  = (const float*)d_in[1];
    const float* norms_r  = (const float*)d_in[2];
    const float* bias     = (const float*)d_in[3];
    const int*   idx_p    = (const int*)d_in[4];
    const int*   idx_r    = (const int*)d_in[5];
    float*       out      = (float*)d_out;

    // workspace: xb (64 MB bf16 [M][K]) | W (32 MB bf16 [N][K])
    short* xb = (short*)d_ws;
    short* wq = (short*)d_ws + (size_t)M_TOTAL * IN_DIM;

    dequant_kernel<<<(OUT_DIM * NGROUPS) / 4, 256, 0, stream>>>(
        norms_p, norms_r, idx_p, idx_r, wq);

    cast_kernel<<<(int)(((size_t)M_TOTAL * IN_DIM) / (256 * 8)), 256, 0, stream>>>(x, xb);

    gemm_kernel<<<(M_TOTAL / BM) * (OUT_DIM / BN), 512, 0, stream>>>(xb, wq, bias, out);
}